// Round 6
// baseline (1528.023 us; speedup 1.0000x reference)
//
#include <hip/hip_runtime.h>
#include <math.h>

namespace {

constexpr int kB   = 8;
constexpr int kL   = 256;
constexpr int kTok = 2048;   // B*L
constexpr int kDM  = 384;
constexpr int kDI  = 768;
constexpr int kDS  = 16;
constexpr int kDTR = 24;
constexpr int kPROJ = 56;    // DTR + 2*DS
constexpr int kNL  = 12;

constexpr int kWIN  = 2 * kDI * kDM;   // 589824 in_proj weights/layer
constexpr int kWOUT = kDM * kDI;       // 294912
constexpr int kWX   = kPROJ * kDI;     // 43008
constexpr int kWTOT = kWIN + kWOUT + kWX;  // 927744

typedef float f32x4 __attribute__((ext_vector_type(4)));
typedef short short8 __attribute__((ext_vector_type(8)));

__device__ __forceinline__ float softplus_f(float x) {
  return (x > 20.f) ? x : log1pf(__expf(x));
}
__device__ __forceinline__ float silu_f(float x) {
  return x / (1.f + __expf(-x));
}
__device__ __forceinline__ unsigned short f2bf(float f) {
  union { float f; unsigned u; } v; v.f = f;
  unsigned r = v.u + 0x7FFFu + ((v.u >> 16) & 1u);
  return (unsigned short)(r >> 16);
}

// ------------- patch embed GEMM: tok = im2col(x)·patch_w^T + b + pos -------
__global__ __launch_bounds__(256) void patch_gemm_k(
    const float* __restrict__ x, const float* __restrict__ Bw,
    const float* __restrict__ bias, const float* __restrict__ pos,
    float* __restrict__ C) {
  __shared__ float As[16][68];
  __shared__ float Bs[16][68];
  int tid = threadIdx.x;
  int bm = blockIdx.y * 64;
  int bn = blockIdx.x * 64;
  int lr = tid >> 2;
  int lk = (tid & 3) << 2;
  int tm = (tid >> 4) << 2;
  int tn = (tid & 15) << 2;
  float acc[4][4] = {};
  for (int k0 = 0; k0 < 256; k0 += 16) {
    {
      int token = bm + lr;
      int b = token >> 8, l = token & 255;
      int h = l >> 3, w = l & 7;
      int p = k0 >> 4;
      const float* ap = x + ((size_t)(b * 512) + h * 16 + p) * 128 + w * 16 + lk;
      float4 av = *(const float4*)ap;
      As[lk + 0][lr] = av.x; As[lk + 1][lr] = av.y;
      As[lk + 2][lr] = av.z; As[lk + 3][lr] = av.w;
    }
    {
      const float* bp = Bw + (size_t)(bn + lr) * 256 + k0 + lk;
      float4 bv = *(const float4*)bp;
      Bs[lk + 0][lr] = bv.x; Bs[lk + 1][lr] = bv.y;
      Bs[lk + 2][lr] = bv.z; Bs[lk + 3][lr] = bv.w;
    }
    __syncthreads();
    #pragma unroll
    for (int k = 0; k < 16; ++k) {
      float4 a = *(const float4*)&As[k][tm];
      float4 b = *(const float4*)&Bs[k][tn];
      float av[4] = {a.x, a.y, a.z, a.w};
      float bv[4] = {b.x, b.y, b.z, b.w};
      #pragma unroll
      for (int i = 0; i < 4; ++i)
        #pragma unroll
        for (int j = 0; j < 4; ++j)
          acc[i][j] = fmaf(av[i], bv[j], acc[i][j]);
    }
    __syncthreads();
  }
  #pragma unroll
  for (int i = 0; i < 4; ++i) {
    int row = bm + tm + i;
    #pragma unroll
    for (int j = 0; j < 4; ++j) {
      int col = bn + tn + j;
      C[(size_t)row * kDM + col] =
          acc[i][j] + bias[col] + pos[(size_t)(row & 255) * kDM + col];
    }
  }
}

// ------------- layernorm over DM=384; bf16 out; optionally zero proj -------
template <bool BF16OUT>
__global__ __launch_bounds__(384) void ln_k(
    const float* __restrict__ in, void* __restrict__ outv,
    const float* __restrict__ g, const float* __restrict__ bb,
    float* __restrict__ proj_zero) {
  int t = blockIdx.x, d = threadIdx.x;
  if (proj_zero && d < kPROJ) proj_zero[(size_t)t * kPROJ + d] = 0.f;
  float v = in[(size_t)t * kDM + d];
  float s = v, s2 = v * v;
  #pragma unroll
  for (int m = 32; m >= 1; m >>= 1) {
    s  += __shfl_xor(s, m);
    s2 += __shfl_xor(s2, m);
  }
  __shared__ float ps[6], ps2[6];
  if ((d & 63) == 0) { ps[d >> 6] = s; ps2[d >> 6] = s2; }
  __syncthreads();
  float S = 0.f, S2 = 0.f;
  #pragma unroll
  for (int i = 0; i < 6; ++i) { S += ps[i]; S2 += ps2[i]; }
  float mean = S * (1.f / 384.f);
  float var  = S2 * (1.f / 384.f) - mean * mean;
  float r = rsqrtf(var + 1e-5f);
  float o = (v - mean) * r * g[d] + bb[d];
  if (BF16OUT) ((unsigned short*)outv)[(size_t)t * kDM + d] = f2bf(o);
  else ((float*)outv)[(size_t)t * kDM + d] = o;
}

// ------------- convert ALL layers' GEMM weights fp32 -> bf16 ---------------
__global__ __launch_bounds__(256) void convert_all_k(
    const float* __restrict__ w_in, const float* __restrict__ w_out,
    const float* __restrict__ w_x, unsigned short* __restrict__ dst) {
  int layer = blockIdx.y;
  int i4 = (blockIdx.x * 256 + threadIdx.x) * 4;
  if (i4 >= kWTOT) return;
  const float* src;
  int off;
  if (i4 < kWIN) { src = w_in + (size_t)layer * kWIN; off = i4; }
  else if (i4 < kWIN + kWOUT) { src = w_out + (size_t)layer * kWOUT; off = i4 - kWIN; }
  else { src = w_x + (size_t)layer * kWX; off = i4 - kWIN - kWOUT; }
  float4 v = *(const float4*)(src + off);
  unsigned short o[4] = {f2bf(v.x), f2bf(v.y), f2bf(v.z), f2bf(v.w)};
  *(uint2*)(dst + (size_t)layer * kWTOT + i4) = *(const uint2*)o;
}

// ------------- bf16 MFMA NT GEMM: C[M,N] fp32 = A[M,K]·B[N,K]^T ------------
// EPIL 0: plain store. EPIL 1: atomicAdd (split-K / residual).
// EPIL 2: atomicAdd into projT[b][col][l] transposed layout.
template <int BN, int EPIL>
__global__ __launch_bounds__(256) void bgemm_k(
    const unsigned short* __restrict__ A, int lda,
    const unsigned short* __restrict__ B, int ldb,
    float* __restrict__ C, int ldc, int N, int Kc) {
  __shared__ __align__(16) unsigned short As[4][128][8];
  __shared__ __align__(16) unsigned short Bs[4][BN][8];
  int tid = threadIdx.x;
  int bm = blockIdx.y * 128;
  int bn = blockIdx.x * BN;
  int k_begin = blockIdx.z * Kc;
  int wave = tid >> 6, lane = tid & 63;
  int lm = lane & 15, lq = lane >> 4;
  int wm, wn;
  if (BN == 128) { wm = (wave >> 1) * 64; wn = (wave & 1) * 64; }
  else           { wm = wave * 32;        wn = 0; }
  constexpr int MT = (BN == 128) ? 4 : 2;
  f32x4 acc[MT][4] = {};

  for (int kt = 0; kt < Kc; kt += 32) {
    int k0 = k_begin + kt;
    int ar0 = tid & 127, aq0 = tid >> 7;
    int aq1 = aq0 + 2;
    uint4 a0 = *(const uint4*)(A + (size_t)(bm + ar0) * lda + k0 + aq0 * 8);
    uint4 a1 = *(const uint4*)(A + (size_t)(bm + ar0) * lda + k0 + aq1 * 8);
    uint4 b0, b1;
    int br0, bq0, br1 = 0, bq1 = 0;
    if (BN == 128) {
      br0 = tid & 127; bq0 = tid >> 7; br1 = br0; bq1 = bq0 + 2;
      b0 = *(const uint4*)(B + (size_t)(bn + br0) * ldb + k0 + bq0 * 8);
      b1 = *(const uint4*)(B + (size_t)(bn + br1) * ldb + k0 + bq1 * 8);
    } else {
      br0 = tid & 63; bq0 = tid >> 6;
      if (bn + br0 < N)
        b0 = *(const uint4*)(B + (size_t)(bn + br0) * ldb + k0 + bq0 * 8);
      else
        b0 = make_uint4(0u, 0u, 0u, 0u);
    }
    __syncthreads();
    *(uint4*)&As[aq0][ar0][0] = a0;
    *(uint4*)&As[aq1][ar0][0] = a1;
    *(uint4*)&Bs[bq0][br0][0] = b0;
    if (BN == 128) *(uint4*)&Bs[bq1][br1][0] = b1;
    __syncthreads();

    short8 bfrag[4];
    #pragma unroll
    for (int ni = 0; ni < 4; ++ni)
      bfrag[ni] = *(const short8*)&Bs[lq][wn + ni * 16 + lm][0];
    #pragma unroll
    for (int mi = 0; mi < MT; ++mi) {
      short8 afrag = *(const short8*)&As[lq][wm + mi * 16 + lm][0];
      #pragma unroll
      for (int ni = 0; ni < 4; ++ni)
        acc[mi][ni] = __builtin_amdgcn_mfma_f32_16x16x32_bf16(
            afrag, bfrag[ni], acc[mi][ni], 0, 0, 0);
    }
  }

  #pragma unroll
  for (int mi = 0; mi < MT; ++mi) {
    #pragma unroll
    for (int ni = 0; ni < 4; ++ni) {
      int grow0 = bm + wm + mi * 16 + lq * 4;
      int gcol = bn + wn + ni * 16 + lm;
      #pragma unroll
      for (int r = 0; r < 4; ++r) {
        float v = acc[mi][ni][r];
        int grow = grow0 + r;
        if (EPIL == 0) {
          C[(size_t)grow * ldc + gcol] = v;
        } else if (EPIL == 1) {
          if (gcol < N) atomicAdd(&C[(size_t)grow * ldc + gcol], v);
        } else {
          if (gcol < N)
            atomicAdd(&C[((size_t)(grow >> 8) * kPROJ + gcol) * kL + (grow & 255)], v);
        }
      }
    }
  }
}

// ------------- causal depthwise conv (DC=4) + SiLU + z-gate ----------------
__global__ __launch_bounds__(256) void conv_tr_k(
    const float* __restrict__ xz, const float* __restrict__ cw,
    const float* __restrict__ cb, float* __restrict__ uT,
    float* __restrict__ sgT, unsigned short* __restrict__ u_bf) {
  int b = blockIdx.y;
  int l0 = blockIdx.x * 16;
  int tid = threadIdx.x;
  #pragma unroll
  for (int ch = 0; ch < 3; ++ch) {
    int d = ch * 256 + tid;
    float w0 = cw[d * 4], w1 = cw[d * 4 + 1], w2 = cw[d * 4 + 2], w3 = cw[d * 4 + 3];
    float bias = cb[d];
    float v[19];
    #pragma unroll
    for (int j = 0; j < 19; ++j) {
      int l = l0 - 3 + j;
      v[j] = (l >= 0) ? xz[(size_t)(b * kL + l) * (2 * kDI) + d] : 0.f;
    }
    float* up = uT + ((size_t)b * kDI + d) * kL + l0;
    float* sp = sgT + ((size_t)b * kDI + d) * kL + l0;
    #pragma unroll
    for (int i = 0; i < 16; ++i) {
      float acc = bias;
      acc = fmaf(v[i], w0, acc);
      acc = fmaf(v[i + 1], w1, acc);
      acc = fmaf(v[i + 2], w2, acc);
      acc = fmaf(v[i + 3], w3, acc);
      float o = silu_f(acc);
      up[i] = o;
      u_bf[(size_t)(b * kL + l0 + i) * kDI + d] = f2bf(o);
      float zv = xz[(size_t)(b * kL + l0 + i) * (2 * kDI) + kDI + d];
      sp[i] = silu_f(zv);
    }
  }
}

// ------------- fused dt_proj + chunked selective scan (projT layout) -------
// projT[b][56][256]: rows 0:24 dt, 24:40 B, 40:56 C. yT out is bf16.
__global__ __launch_bounds__(256) void scan3_k(
    const float* __restrict__ projT, const float* __restrict__ uT,
    const float* __restrict__ sgT, const float* __restrict__ dtw,
    const float* __restrict__ dtb, const float* __restrict__ A_log,
    const float* __restrict__ Dsk, unsigned short* __restrict__ yT) {
  int d = blockIdx.x;   // 0..767
  int b = blockIdx.y;   // 0..7
  int tid = threadIdx.x;
  int c = tid >> 4;     // chunk
  int n = tid & 15;     // state
  __shared__ float sd[256], su[256], sg[256];
  __shared__ unsigned short sy[256];
  __shared__ float sh_h[16][17], sh_a[16][17];
  __shared__ float swdt[24];
  size_t rbase = ((size_t)b * kDI + d) * kL;
  su[tid] = uT[rbase + tid];
  sg[tid] = sgT[rbase + tid];
  if (tid < kDTR) swdt[tid] = dtw[(size_t)d * kDTR + tid];
  float bdt = dtb[d];
  float Aval = -__expf(A_log[d * kDS + n]);
  const float* pb = projT + (size_t)b * kPROJ * kL;
  // vectorized B/C loads for this (c,n): contiguous in l
  float4 Bv4[4], Cv4[4];
  {
    const float* prB = pb + (size_t)(24 + n) * kL + c * 16;
    const float* prC = pb + (size_t)(40 + n) * kL + c * 16;
    #pragma unroll
    for (int q = 0; q < 4; ++q) {
      Bv4[q] = ((const float4*)prB)[q];
      Cv4[q] = ((const float4*)prC)[q];
    }
  }
  float B_[16], C_[16];
  #pragma unroll
  for (int q = 0; q < 4; ++q) {
    B_[q * 4 + 0] = Bv4[q].x; B_[q * 4 + 1] = Bv4[q].y;
    B_[q * 4 + 2] = Bv4[q].z; B_[q * 4 + 3] = Bv4[q].w;
    C_[q * 4 + 0] = Cv4[q].x; C_[q * 4 + 1] = Cv4[q].y;
    C_[q * 4 + 2] = Cv4[q].z; C_[q * 4 + 3] = Cv4[q].w;
  }
  __syncthreads();
  // delta for l = tid (coalesced projT rows)
  {
    float acc = bdt;
    #pragma unroll
    for (int r = 0; r < kDTR; ++r)
      acc = fmaf(pb[(size_t)r * kL + tid], swdt[r], acc);
    sd[tid] = softplus_f(acc);
  }
  __syncthreads();

  float h = 0.f, ca = 1.f;
  float h_reg[16], ca_reg[16];
  #pragma unroll
  for (int i = 0; i < 16; ++i) {
    int l = c * 16 + i;
    float dl = sd[l];
    float a = __expf(dl * Aval);
    h = fmaf(a, h, (dl * su[l]) * B_[i]);
    ca *= a;
    h_reg[i] = h;
    ca_reg[i] = ca;
  }
  sh_h[c][n] = h;
  sh_a[c][n] = ca;
  __syncthreads();

  float h0 = 0.f;
  for (int j = 0; j < c; ++j) h0 = fmaf(sh_a[j][n], h0, sh_h[j][n]);

  float Dv = Dsk[d];
  #pragma unroll
  for (int i = 0; i < 16; ++i) {
    int l = c * 16 + i;
    float yv = fmaf(ca_reg[i], h0, h_reg[i]) * C_[i];
    yv += __shfl_xor(yv, 1);
    yv += __shfl_xor(yv, 2);
    yv += __shfl_xor(yv, 4);
    yv += __shfl_xor(yv, 8);
    if (n == 0) sy[l] = f2bf((yv + su[l] * Dv) * sg[l]);
  }
  __syncthreads();
  yT[rbase + tid] = sy[tid];
}

// ------------- transpose yT [b][768][256] bf16 -> y_bf [2048][768] bf16 ----
__global__ __launch_bounds__(256) void transpose_bf_k(
    const unsigned short* __restrict__ yT, unsigned short* __restrict__ ybf) {
  int b = blockIdx.z;
  int db = blockIdx.y;   // 12 tiles of 64 d
  int lb = blockIdx.x;   // 4 tiles of 64 l
  __shared__ float tile[64][65];
  int tid = threadIdx.x;
  int lx = tid & 63, dq = tid >> 6;
  const unsigned short* src = yT + ((size_t)b * kDI + db * 64) * kL + lb * 64;
  #pragma unroll
  for (int i = 0; i < 16; ++i) {
    int dd = dq * 16 + i;
    unsigned ui = (unsigned)src[(size_t)dd * kL + lx] << 16;
    tile[dd][lx] = __uint_as_float(ui);
  }
  __syncthreads();
  int ly = tid >> 2, dx0 = (tid & 3) * 16;
  unsigned short tmp[16];
  #pragma unroll
  for (int i = 0; i < 16; ++i)
    tmp[i] = (unsigned short)(__float_as_uint(tile[dx0 + i][ly]) >> 16);
  unsigned short* dst =
      ybf + (size_t)(b * kL + lb * 64 + ly) * kDI + db * 64 + dx0;
  *(uint4*)dst = *(const uint4*)tmp;
  *(uint4*)(dst + 8) = *(const uint4*)(tmp + 8);
}

// ---------------- mean pool over L ----------------
__global__ __launch_bounds__(384) void pool_k(
    const float* __restrict__ h, float* __restrict__ pooled) {
  int b = blockIdx.x, d = threadIdx.x;
  float acc = 0.f;
  for (int l = 0; l < kL; ++l) acc += h[(size_t)(b * kL + l) * kDM + d];
  pooled[b * kDM + d] = acc * (1.f / 256.f);
}

// ---------------- head ----------------
__global__ __launch_bounds__(64) void head_k(
    const float* __restrict__ pooled, const float* __restrict__ hw,
    const float* __restrict__ hb, float* __restrict__ out) {
  int b = blockIdx.x >> 2, c = blockIdx.x & 3;
  int lane = threadIdx.x;
  float acc = 0.f;
  for (int dd = lane; dd < kDM; dd += 64)
    acc = fmaf(pooled[b * kDM + dd], hw[c * kDM + dd], acc);
  #pragma unroll
  for (int m = 32; m >= 1; m >>= 1) acc += __shfl_xor(acc, m);
  if (lane == 0) out[b * 4 + c] = acc + hb[c];
}

}  // namespace

extern "C" void kernel_launch(void* const* d_in, const int* in_sizes, int n_in,
                              void* d_out, int out_size, void* d_ws, size_t ws_size,
                              hipStream_t stream) {
  (void)in_sizes; (void)n_in; (void)out_size; (void)ws_size;
  const float* x        = (const float*)d_in[0];
  const float* patch_w  = (const float*)d_in[1];
  const float* patch_b  = (const float*)d_in[2];
  const float* pos      = (const float*)d_in[3];
  const float* ln_g     = (const float*)d_in[4];
  const float* ln_b     = (const float*)d_in[5];
  const float* in_w     = (const float*)d_in[6];
  const float* conv_w   = (const float*)d_in[7];
  const float* conv_b   = (const float*)d_in[8];
  const float* xproj_w  = (const float*)d_in[9];
  const float* dtproj_w = (const float*)d_in[10];
  const float* dtproj_b = (const float*)d_in[11];
  const float* A_log    = (const float*)d_in[12];
  const float* Dskip    = (const float*)d_in[13];
  const float* out_w    = (const float*)d_in[14];
  const float* fn_g     = (const float*)d_in[15];
  const float* fn_b     = (const float*)d_in[16];
  const float* head_w   = (const float*)d_in[17];
  const float* head_b   = (const float*)d_in[18];
  float* out = (float*)d_out;

  float* ws = (float*)d_ws;
  float* tok    = ws; ws += kTok * kDM;       // fp32 residual
  float* xz     = ws; ws += kTok * 2 * kDI;
  float* uT     = ws; ws += kTok * kDI;
  float* sgT    = ws; ws += kTok * kDI;
  float* projT  = ws; ws += kTok * kPROJ;     // [b][56][256]
  float* pooled = ws; ws += kB * kDM;
  unsigned short* yT_bf = (unsigned short*)ws; ws += kTok * kDI / 2;
  unsigned short* h_bf  = (unsigned short*)ws; ws += kTok * kDM / 2;
  unsigned short* y_bf  = (unsigned short*)ws; ws += kTok * kDI / 2;
  unsigned short* u_bf  = (unsigned short*)ws; ws += kTok * kDI / 2;
  unsigned short* w_bf  = (unsigned short*)ws; ws += (size_t)kNL * kWTOT / 2;
  float* lnout = xz;  // overlay: xz dead after last conv

  // all-layer weight cast (once per call)
  convert_all_k<<<dim3(kWTOT / 4 / 256, kNL), 256, 0, stream>>>(
      in_w, out_w, xproj_w, w_bf);

  // Patch embedding fused: im2col + GEMM + bias + pos
  patch_gemm_k<<<dim3(6, 32), 256, 0, stream>>>(x, patch_w, patch_b, pos, tok);

  for (int layer = 0; layer < kNL; ++layer) {
    const unsigned short* wl = w_bf + (size_t)layer * kWTOT;
    // LN -> bf16 A operand; also zeroes projT for this layer's split-K GEMM
    ln_k<true><<<kTok, kDM, 0, stream>>>(tok, h_bf, ln_g + layer * kDM,
                                         ln_b + layer * kDM, projT);
    // in_proj (MFMA): [2048,384]x[1536,384]^T -> xz fp32
    bgemm_k<128, 0><<<dim3(12, 16, 1), 256, 0, stream>>>(
        h_bf, kDM, wl, kDM, xz, 2 * kDI, 2 * kDI, kDM);
    // depthwise causal conv + SiLU + z-gate -> uT, sgT fp32; u_bf bf16
    conv_tr_k<<<dim3(16, kB), 256, 0, stream>>>(
        xz, conv_w + layer * kDI * 4, conv_b + layer * kDI, uT, sgT, u_bf);
    // x_proj (MFMA, split-K=12, transposed atomic): -> projT[b][56][256]
    bgemm_k<64, 2><<<dim3(1, 16, 12), 256, 0, stream>>>(
        u_bf, kDI, wl + kWIN + kWOUT, kDI, projT, 0, kPROJ, kDI / 12);
    // fused dt_proj + selective scan + skip + gate -> yT_bf [b][d][l]
    scan3_k<<<dim3(kDI, kB), 256, 0, stream>>>(
        projT, uT, sgT, dtproj_w + (size_t)layer * kDI * kDTR,
        dtproj_b + layer * kDI, A_log + (size_t)layer * kDI * kDS,
        Dskip + layer * kDI, yT_bf);
    // transpose yT_bf -> y_bf [2048,768]
    transpose_bf_k<<<dim3(4, 12, kB), 256, 0, stream>>>(yT_bf, y_bf);
    // out_proj (MFMA, split-K=4, atomic into residual): tok += y x W^T
    bgemm_k<128, 1><<<dim3(3, 16, 4), 256, 0, stream>>>(
        y_bf, kDI, wl + kWIN, kDI, tok, kDM, kDM, kDI / 4);
  }

  ln_k<false><<<kTok, kDM, 0, stream>>>(tok, lnout, fn_g, fn_b, nullptr);
  pool_k<<<kB, kDM, 0, stream>>>(lnout, pooled);
  head_k<<<kB * 4, 64, 0, stream>>>(pooled, head_w, head_b, out);
}